// Round 7
// baseline (665.421 us; speedup 1.0000x reference)
//
#include <hip/hip_runtime.h>
#include <math.h>

// GatedMDTA: B=2, C=192, H=W=256, HEADS=6, hd=32, QC=768.
// Round 12: de-stage W from LDS in gemm_t and proj_fused.
// Round-11 post-mortem: proj_fused 93us, MfmaUtil 4.7, VALUBusy 27, HBM 20%,
// occupancy 30% (LDS 50KB -> 3 blocks/CU) => latency-bound, not enough waves
// to hide ~100 scalar L2/HBM loads per lane; 8 full-drain barriers per block.
// Fix: W (0.38MB, L2-resident; 25KB m-tile fits L1) is read as bf16x8
// fragments directly from global. a_lds deleted -> LDS 25.6KB (6 blocks/CU
// by LDS), ONE barrier per block, no staging instructions. Applied to both
// gemm_t and proj_fused. Sigmoid uses __expf. Everything else = round 11.
//
// ws layout: xT 52.43MB | wbf 0.38MB | pre 4q | post 4q | post2 4q |
//            S/ssq floats | Pbf bf16.  Total ~330MB < 402MB ws.

#define HEADS 6
#define CDIM 192
#define QCH 768
#define HH 256
#define WW 256
#define NPIX 65536
#define PADC 200   // padded channel row stride (ushorts)

typedef __bf16 bf16x8 __attribute__((ext_vector_type(8)));
typedef float f32x4 __attribute__((ext_vector_type(4)));
typedef unsigned short u16x8 __attribute__((ext_vector_type(8)));

__device__ __forceinline__ float b2f(unsigned short u) {
  union { unsigned int i; float f; } x; x.i = ((unsigned int)u) << 16; return x.f;
}
__device__ __forceinline__ unsigned short f2b(float f) {
  union { float f; unsigned int i; } x; x.f = f;
  unsigned int lsb = (x.i >> 16) & 1u;
  x.i += 0x7fffu + lsb;           // round-to-nearest-even
  return (unsigned short)(x.i >> 16);
}

// ---------------- zero-init small fp32 scratch
__global__ void zero_init(float* __restrict__ p, int n) {
  int i = blockIdx.x * 256 + threadIdx.x;
  if (i < n) p[i] = 0.f;
}

// ---------------- weights fp32 -> bf16, padded rows [5][192][200]
// q 0..3 = qkv quarters, q 4 = proj.
__global__ __launch_bounds__(256)
void w2bf(const float* __restrict__ qkv_w, const float* __restrict__ proj_w,
          unsigned short* __restrict__ wbf) {
  int id = blockIdx.x * 256 + threadIdx.x;      // < 5*192*192 = 184320
  if (id >= 5 * 192 * 192) return;
  int k = id % 192;
  int m = (id / 192) % 192;
  int q = id / (192 * 192);
  float v = (q < 4) ? qkv_w[(size_t)(q * 192 + m) * 192 + k]
                    : proj_w[(size_t)m * 192 + k];
  wbf[((size_t)q * 192 + m) * PADC + k] = f2b(v);
}

// ---------------- x fp32 [b][c][n] -> xT bf16 [b][n][PADC]  (transpose)
__global__ __launch_bounds__(256)
void x2t(const float* __restrict__ x, unsigned short* __restrict__ xT) {
  __shared__ unsigned short tile[64 * PADC];
  int t = threadIdx.x;
  int n0 = blockIdx.x * 64;
  int b = blockIdx.y;
  #pragma unroll
  for (int i = 0; i < 12; ++i) {
    int idx = t + i * 256;                 // 0..3071 float4 chunks
    int c = idx >> 4;                      // 0..191
    int nn4 = (idx & 15) << 2;             // 0..60
    float4 v = *(const float4*)(x + ((size_t)b * CDIM + c) * NPIX + n0 + nn4);
    tile[(nn4 + 0) * PADC + c] = f2b(v.x);
    tile[(nn4 + 1) * PADC + c] = f2b(v.y);
    tile[(nn4 + 2) * PADC + c] = f2b(v.z);
    tile[(nn4 + 3) * PADC + c] = f2b(v.w);
  }
  __syncthreads();
  #pragma unroll
  for (int i = 0; i < 6; ++i) {
    int idx = t + i * 256;                 // 0..1535 : 64 rows x 24 chunks
    int row = idx / 24;
    int c8 = (idx % 24) * 8;
    *(u16x8*)(xT + ((size_t)b * NPIX + n0 + row) * PADC + c8) =
        *(const u16x8*)(tile + row * PADC + c8);
  }
}

// ---------------- qkv GEMM, transpose-free, W read direct from global.
// A-op = pixels (xT), B-op = W. Bsrc is [b][n][PADC]. NMT m-tiles per block.
// Output c-major bf16 quarter slots: [b*2+half][192][N]. ONE barrier total.
template <int NMT>
__global__ __launch_bounds__(256)
void gemm_t(const unsigned short* __restrict__ wq0,   // [192][PADC] bf16
            const unsigned short* __restrict__ wq1,   // [192][PADC] bf16
            const float* __restrict__ bias0,          // [192]
            const float* __restrict__ bias1,          // [192]
            const unsigned short* __restrict__ Bsrc,  // [2][NPIX][PADC] bf16
            unsigned short* __restrict__ outB)        // [4][192][N] bf16
{
  __shared__ unsigned short b_lds[64 * PADC];   // pixel tile (64 n x 192 c)
  int t = threadIdx.x;
  int n0 = blockIdx.x * 64;
  int b = blockIdx.y;

  // stage pixel tile: one contiguous 64*PADC region, linear 16B copies
  const unsigned short* Bs = Bsrc + ((size_t)b * NPIX + n0) * PADC;
  #pragma unroll
  for (int i = 0; i < 6; ++i) {
    int idx = t + i * 256;
    *(u16x8*)(b_lds + idx * 8) = *(const u16x8*)(Bs + (size_t)idx * 8);
  }
  if (t < 64) {
    int idx = 1536 + t;
    *(u16x8*)(b_lds + idx * 8) = *(const u16x8*)(Bs + (size_t)idx * 8);
  }
  __syncthreads();

  int wid = t >> 6, lane = t & 63;
  int r = lane & 15, quad = lane >> 4;

  #pragma unroll
  for (int mt = 0; mt < NMT; ++mt) {
    int half = mt / 3;                  // which quarter (0: wq0, 1: wq1)
    int mrow = (mt % 3) * 64;           // m-tile base within the 192-row quarter
    const unsigned short* wq = (half ? wq1 : wq0) + (size_t)mrow * PADC;

    f32x4 acc[4];
    #pragma unroll
    for (int nt = 0; nt < 4; ++nt) acc[nt] = (f32x4){0.f, 0.f, 0.f, 0.f};

    #pragma unroll
    for (int kk = 0; kk < 192; kk += 32) {
      bf16x8 xf = *(const bf16x8*)(b_lds + (wid * 16 + r) * PADC + kk + quad * 8);
      #pragma unroll
      for (int nt = 0; nt < 4; ++nt) {
        // W fragment direct from global (L1/L2-resident, 16B/lane)
        bf16x8 wf = *(const bf16x8*)(wq + (size_t)(nt * 16 + r) * PADC + kk + quad * 8);
        acc[nt] = __builtin_amdgcn_mfma_f32_16x16x32_bf16(xf, wf, acc[nt], 0, 0, 0);
      }
    }

    // D: row(M=n) = quad*4+i, col(N=m) = lane&15. Per lane: 4 consecutive n.
    const float* bp = half ? bias1 : bias0;
    size_t n = (size_t)n0 + wid * 16 + quad * 4;
    unsigned short* op = outB + (size_t)(b * 2 + half) * CDIM * NPIX;
    #pragma unroll
    for (int nt = 0; nt < 4; ++nt) {
      int m = mrow + nt * 16 + r;
      float bb = bp[m];
      ushort4 uu;
      uu.x = f2b(acc[nt][0] + bb); uu.y = f2b(acc[nt][1] + bb);
      uu.z = f2b(acc[nt][2] + bb); uu.w = f2b(acc[nt][3] + bb);
      *(ushort4*)(op + (size_t)m * NPIX + n) = uu;
    }
  }
}

// ---------------- proj with fused PV+gate B-stage; W direct from global.
// Per block (64-pixel tile, batch b): for each head h, compute the att^T
// sub-tile D[c=32][n=64] = P[h] @ v[h] via MFMA (A=P bf16 from global,
// B=v via 8 u16 global reads per lane), multiply by sigmoid(gate), write
// b_lds[n][c]. ONE barrier, then 3 m-tiles of barrier-free MFMA with W
// fragments from global; fp32 out c-major.
__global__ __launch_bounds__(256)
void proj_fused(const unsigned short* __restrict__ wproj,  // [192][PADC] bf16
                const float* __restrict__ bias,            // [192]
                const unsigned short* __restrict__ post2,  // [4][192][N]: b*2+{0:v,1:g}
                const unsigned short* __restrict__ Pbf,    // [2][HEADS][32][32] bf16 [c][d]
                float* __restrict__ out)                   // [2][192][N] fp32
{
  __shared__ unsigned short b_lds[64 * PADC];   // att^T tile [n][c]
  int t = threadIdx.x;
  int n0 = blockIdx.x * 64;
  int b = blockIdx.y;
  int wid = t >> 6, lane = t & 63;
  int r = lane & 15, quad = lane >> 4;
  int nl = wid * 16 + r;                        // local n this lane owns
  size_t n = (size_t)n0 + nl;

  const unsigned short* vbase = post2 + (size_t)(b * 2 + 0) * CDIM * NPIX;
  const unsigned short* gbase = post2 + (size_t)(b * 2 + 1) * CDIM * NPIX;
  const unsigned short* Pb = Pbf + (size_t)b * HEADS * 1024;

  #pragma unroll
  for (int h = 0; h < HEADS; ++h) {
    // B-frag: v[k=quad*8+j][n], k within head h
    union { unsigned short u[8]; bf16x8 v; } vf;
    #pragma unroll
    for (int j = 0; j < 8; ++j)
      vf.u[j] = vbase[(size_t)(h * 32 + quad * 8 + j) * NPIX + n];
    #pragma unroll
    for (int c0 = 0; c0 < 32; c0 += 16) {
      // A-frag: P[c0+r][quad*8 .. +7] contiguous bf16x8 (L2-resident)
      bf16x8 pf = *(const bf16x8*)(Pb + h * 1024 + (c0 + r) * 32 + quad * 8);
      f32x4 d = (f32x4){0.f, 0.f, 0.f, 0.f};
      d = __builtin_amdgcn_mfma_f32_16x16x32_bf16(pf, vf.v, d, 0, 0, 0);
      // D: row c = c0 + quad*4 + i, col n = r (this lane's nl)
      #pragma unroll
      for (int i = 0; i < 4; ++i) {
        int c = c0 + quad * 4 + i;
        float gg = b2f(gbase[(size_t)(h * 32 + c) * NPIX + n]);
        float sg = 1.f / (1.f + __expf(-gg));
        b_lds[nl * PADC + h * 32 + c] = f2b(d[i] * sg);
      }
    }
  }

  __syncthreads();                    // b_lds ready; only barrier in kernel

  #pragma unroll
  for (int mt = 0; mt < 3; ++mt) {
    int mrow = mt * 64;
    const unsigned short* wq = wproj + (size_t)mrow * PADC;

    f32x4 acc[4];
    #pragma unroll
    for (int nt = 0; nt < 4; ++nt) acc[nt] = (f32x4){0.f, 0.f, 0.f, 0.f};

    #pragma unroll
    for (int kk = 0; kk < 192; kk += 32) {
      bf16x8 xf = *(const bf16x8*)(b_lds + (wid * 16 + r) * PADC + kk + quad * 8);
      #pragma unroll
      for (int nt = 0; nt < 4; ++nt) {
        bf16x8 wf = *(const bf16x8*)(wq + (size_t)(nt * 16 + r) * PADC + kk + quad * 8);
        acc[nt] = __builtin_amdgcn_mfma_f32_16x16x32_bf16(xf, wf, acc[nt], 0, 0, 0);
      }
    }

    size_t nn = (size_t)n0 + wid * 16 + quad * 4;
    float* op = out + (size_t)b * CDIM * NPIX;
    #pragma unroll
    for (int nt = 0; nt < 4; ++nt) {
      int m = mrow + nt * 16 + r;
      float bb = bias[m];
      float4 vv;
      vv.x = acc[nt][0] + bb; vv.y = acc[nt][1] + bb;
      vv.z = acc[nt][2] + bb; vv.w = acc[nt][3] + bb;
      *(float4*)(op + (size_t)m * NPIX + nn) = vv;
    }
  }
}

// ---------------- 3x3 depthwise conv + bias; optional fused per-channel ssq.
__global__ __launch_bounds__(256)
void dwconv_ssq(const unsigned short* __restrict__ in,   // [z][192][H][W] bf16
                const float* __restrict__ w9,            // [4][192][9] fp32
                const float* __restrict__ bias,          // [4][192] fp32
                unsigned short* __restrict__ outp,       // [z][192][H][W] bf16
                float* __restrict__ ssqBase,             // [2][2][192] or null
                int qs0, int qs1)
{
  __shared__ unsigned short lds[34][256];   // rows y0-1 .. y0+32
  __shared__ float red[4];
  int t = threadIdx.x;
  int z = blockIdx.z;
  int qsel = (z & 1) ? qs1 : qs0;
  int o  = blockIdx.x >> 3;                 // channel 0..191
  int ry = blockIdx.x & 7;                  // row group 0..7
  int y0 = ry << 5;                         // first output row

  const unsigned short* base = in + ((size_t)z * CDIM + o) * NPIX;
  #pragma unroll
  for (int i = 0; i < 9; ++i) {
    int idx = t + i * 256;
    if (idx < 2176) {
      int row = idx >> 6;
      int c4  = (idx & 63) << 2;
      int gy  = y0 - 1 + row;
      ushort4 vv = make_ushort4(0, 0, 0, 0);       // zero-pad y boundary
      if (gy >= 0 && gy < HH)
        vv = *(const ushort4*)(base + (size_t)gy * WW + c4);
      *(ushort4*)(&lds[row][c4]) = vv;
    }
  }

  float wv[9];
  #pragma unroll
  for (int i = 0; i < 9; ++i) wv[i] = w9[((size_t)qsel * CDIM + o) * 9 + i];
  float bo = bias[qsel * CDIM + o];
  __syncthreads();

  int w = t >> 6, lane = t & 63;
  int x0 = lane << 2;                       // 4 columns per lane
  float sumsq = 0.f;
  unsigned short* outbase = outp + ((size_t)z * CDIM + o) * NPIX;

  #pragma unroll
  for (int i = 0; i < 8; ++i) {
    int yo = w * 8 + i;                     // local output row (0..31)
    float a0 = bo, a1 = bo, a2 = bo, a3 = bo;
    #pragma unroll
    for (int dy = 0; dy < 3; ++dy) {
      ushort4 mv = *(const ushort4*)(&lds[yo + dy][x0]);   // ds_read_b64
      float v0 = b2f(mv.x), v1 = b2f(mv.y), v2 = b2f(mv.z), v3 = b2f(mv.w);
      float vl = __shfl_up(v3, 1, 64);   if (lane == 0)  vl = 0.f;  // x=-1
      float vr = __shfl_down(v0, 1, 64); if (lane == 63) vr = 0.f;  // x=256
      float w0 = wv[dy * 3 + 0], w1 = wv[dy * 3 + 1], w2 = wv[dy * 3 + 2];
      a0 += w0 * vl + w1 * v0 + w2 * v1;
      a1 += w0 * v0 + w1 * v1 + w2 * v2;
      a2 += w0 * v1 + w1 * v2 + w2 * v3;
      a3 += w0 * v2 + w1 * v3 + w2 * vr;
    }
    ushort4 ov;
    ov.x = f2b(a0); ov.y = f2b(a1); ov.z = f2b(a2); ov.w = f2b(a3);
    *(ushort4*)(outbase + (size_t)(y0 + yo) * WW + x0) = ov;    // 8B store
    if (ssqBase != nullptr) sumsq += a0 * a0 + a1 * a1 + a2 * a2 + a3 * a3;
  }

  if (ssqBase != nullptr) {                 // uniform per launch
    float* ssq = ssqBase + (size_t)(z >> 1) * 2 * CDIM + (z & 1) * CDIM;
    #pragma unroll
    for (int off = 32; off; off >>= 1) sumsq += __shfl_down(sumsq, off, 64);
    if (lane == 0) red[w] = sumsq;
    __syncthreads();
    if (t == 0) atomicAdd(&ssq[o], red[0] + red[1] + red[2] + red[3]);
  }
}

// ---------------- Gram: S[b][h][c][d] = sum_n q[...]*k[...]  (unchanged)
__global__ __launch_bounds__(256)
void gram(const unsigned short* __restrict__ post,   // [4][192][N] bf16
          float* __restrict__ S)                     // [2][HEADS][32][32]
{
  int h = blockIdx.y, b = blockIdx.z;
  int t = threadIdx.x, wid = t >> 6, lane = t & 63;
  int r = lane & 15, quad = lane >> 4;
  int c0 = (wid >> 1) * 16, d0 = (wid & 1) * 16;
  size_t nb = (size_t)blockIdx.x * 512 + quad * 8;
  const unsigned short* qrow =
      post + ((size_t)(b * 2 + 0) * CDIM + h * 32 + c0 + r) * NPIX + nb;
  const unsigned short* krow =
      post + ((size_t)(b * 2 + 1) * CDIM + h * 32 + d0 + r) * NPIX + nb;
  f32x4 acc = (f32x4){0.f, 0.f, 0.f, 0.f};
  #pragma unroll
  for (int kk = 0; kk < 512; kk += 32) {
    bf16x8 af  = *(const bf16x8*)(qrow + kk);
    bf16x8 bfr = *(const bf16x8*)(krow + kk);
    acc = __builtin_amdgcn_mfma_f32_16x16x32_bf16(af, bfr, acc, 0, 0, 0);
  }
  float* Sp = S + ((size_t)b * HEADS + h) * 1024;
  #pragma unroll
  for (int i = 0; i < 4; ++i)
    atomicAdd(&Sp[(c0 + quad * 4 + i) * 32 + (d0 + r)], acc[i]);
}

// ---------------- scale + softmax; writes P as bf16 [b][h][c][d]
__global__ void softmax_scale(const float* __restrict__ S,    // [2][HEADS][1024]
                              const float* __restrict__ ssq,  // [2][2][192]
                              const float* __restrict__ temp, // [HEADS]
                              unsigned short* __restrict__ Pbf) // [2][HEADS][32][32] bf16
{
  int h = blockIdx.x, b = blockIdx.y;
  int t = threadIdx.x;
  int c = t >> 5, d = t & 31;
  float nq = fmaxf(sqrtf(ssq[(size_t)b * 2 * CDIM + h * 32 + c]), 1e-12f);
  float nk = fmaxf(sqrtf(ssq[(size_t)b * 2 * CDIM + CDIM + h * 32 + d]), 1e-12f);
  float v = S[((size_t)b * HEADS + h) * 1024 + t] / (nq * nk) * temp[h];
  float m = v;
  for (int off = 16; off; off >>= 1) m = fmaxf(m, __shfl_xor(m, off, 32));
  float e = expf(v - m);
  float s = e;
  for (int off = 16; off; off >>= 1) s += __shfl_xor(s, off, 32);
  Pbf[((size_t)b * HEADS + h) * 1024 + c * 32 + d] = f2b(e / s);
}

extern "C" void kernel_launch(void* const* d_in, const int* in_sizes, int n_in,
                              void* d_out, int out_size, void* d_ws, size_t ws_size,
                              hipStream_t stream)
{
  const float* x      = (const float*)d_in[0];
  const float* qkv_w  = (const float*)d_in[1];
  const float* qkv_b  = (const float*)d_in[2];
  const float* dw_w   = (const float*)d_in[3];
  const float* dw_b   = (const float*)d_in[4];
  const float* temp   = (const float*)d_in[5];
  const float* proj_w = (const float*)d_in[6];
  const float* proj_b = (const float*)d_in[7];
  float* out = (float*)d_out;

  char* ws = (char*)d_ws;
  const size_t qbytes  = (size_t)CDIM * NPIX * 2;            // 25,165,824
  const size_t xTbytes = (size_t)2 * NPIX * PADC * 2;        // 52,428,800
  const size_t wbytes  = (size_t)5 * 192 * PADC * 2;         // 384,000
  unsigned short* xT    = (unsigned short*)ws;
  unsigned short* wbf   = (unsigned short*)(ws + xTbytes);
  unsigned short* pre   = (unsigned short*)(ws + xTbytes + wbytes);          // 4 slots
  unsigned short* post  = (unsigned short*)(ws + xTbytes + wbytes + 4 * qbytes);
  unsigned short* post2 = (unsigned short*)(ws + xTbytes + wbytes + 8 * qbytes);
  float* S   = (float*)(ws + xTbytes + wbytes + 12 * qbytes);
  float* ssq = S + 2 * HEADS * 1024;
  unsigned short* Pbf = (unsigned short*)(ssq + 2 * 2 * CDIM);  // [2][6][32][32] bf16
  const int nz = 2 * HEADS * 1024 + 2 * 2 * CDIM;

  zero_init<<<(nz + 255) / 256, 256, 0, stream>>>(S, nz);
  w2bf<<<(5 * 192 * 192 + 255) / 256, 256, 0, stream>>>(qkv_w, proj_w, wbf);
  x2t<<<dim3(NPIX / 64, 2), 256, 0, stream>>>(x, xT);

  const unsigned short* wq = wbf;                      // quarter stride 192*PADC
  const size_t wqs = (size_t)192 * PADC;

  // phase 1: q (quarter 0) + k (quarter 2), both batches -> pre slots b*2+{0,1}
  gemm_t<6><<<dim3(NPIX / 64, 2), 256, 0, stream>>>(
      wq + 0 * wqs, wq + 2 * wqs, qkv_b + 0 * CDIM, qkv_b + 2 * CDIM, xT, pre);
  dwconv_ssq<<<dim3(CDIM * 8, 1, 4), 256, 0, stream>>>(pre, dw_w, dw_b, post, ssq, 0, 2);

  // phase 2: v (quarter 3) + gate (quarter 1) -> pre slots b*2+{0,1}
  gemm_t<6><<<dim3(NPIX / 64, 2), 256, 0, stream>>>(
      wq + 3 * wqs, wq + 1 * wqs, qkv_b + 3 * CDIM, qkv_b + 1 * CDIM, xT, pre);
  dwconv_ssq<<<dim3(CDIM * 8, 1, 4), 256, 0, stream>>>(pre, dw_w, dw_b, post2, nullptr, 3, 1);

  gram<<<dim3(128, HEADS, 2), 256, 0, stream>>>(post, S);
  softmax_scale<<<dim3(HEADS, 2), 1024, 0, stream>>>(S, ssq, temp, Pbf);

  // proj with fused PV+gate B-stage, fp32 out c-major
  proj_fused<<<dim3(NPIX / 64, 2), 256, 0, stream>>>(
      wq + 4 * wqs, proj_b, post2, Pbf, out);
}

// Round 8
// 512.446 us; speedup vs baseline: 1.2985x; 1.2985x over previous
//
#include <hip/hip_runtime.h>
#include <math.h>

// GatedMDTA: B=2, C=192, H=W=256, HEADS=6, hd=32, QC=768.
// Round 13: revert round-12's W-de-staging (regressed 507->665: W frags read
// per-MFMA from VMEM = 144 dependent 400B-strided loads/lane, latency-bound
// at MfmaUtil 5%, VALU 6%) and instead hold W in REGISTERS: 24 bf16x8 frags
// (96 VGPR) loaded once per block. gemm_t block = (m-tile, 4 n-tiles): loop
// {stage pixel tile -> barrier -> 6 ds_read + 24 MFMA (W from regs) ->
// stores -> barrier}. Per-lane LDS reads drop 30->6 per tile; no W staging,
// no a_lds, LDS 25.6KB. proj_fused reverted to round-11 form (93us known
// good; keeps __expf). Everything else = round 11 (507us).
//
// ws layout: xT 52.43MB | wbf 0.38MB | pre 4q | post 4q | post2 4q |
//            S/ssq floats | Pbf bf16.  Total ~330MB < 402MB ws.

#define HEADS 6
#define CDIM 192
#define QCH 768
#define HH 256
#define WW 256
#define NPIX 65536
#define PADC 200   // padded channel row stride (ushorts)
#define GNT 4      // n-tiles per gemm_t block

typedef __bf16 bf16x8 __attribute__((ext_vector_type(8)));
typedef float f32x4 __attribute__((ext_vector_type(4)));
typedef unsigned short u16x8 __attribute__((ext_vector_type(8)));

__device__ __forceinline__ float b2f(unsigned short u) {
  union { unsigned int i; float f; } x; x.i = ((unsigned int)u) << 16; return x.f;
}
__device__ __forceinline__ unsigned short f2b(float f) {
  union { float f; unsigned int i; } x; x.f = f;
  unsigned int lsb = (x.i >> 16) & 1u;
  x.i += 0x7fffu + lsb;           // round-to-nearest-even
  return (unsigned short)(x.i >> 16);
}

// ---------------- zero-init small fp32 scratch
__global__ void zero_init(float* __restrict__ p, int n) {
  int i = blockIdx.x * 256 + threadIdx.x;
  if (i < n) p[i] = 0.f;
}

// ---------------- weights fp32 -> bf16, padded rows [5][192][200]
// q 0..3 = qkv quarters, q 4 = proj.
__global__ __launch_bounds__(256)
void w2bf(const float* __restrict__ qkv_w, const float* __restrict__ proj_w,
          unsigned short* __restrict__ wbf) {
  int id = blockIdx.x * 256 + threadIdx.x;      // < 5*192*192 = 184320
  if (id >= 5 * 192 * 192) return;
  int k = id % 192;
  int m = (id / 192) % 192;
  int q = id / (192 * 192);
  float v = (q < 4) ? qkv_w[(size_t)(q * 192 + m) * 192 + k]
                    : proj_w[(size_t)m * 192 + k];
  wbf[((size_t)q * 192 + m) * PADC + k] = f2b(v);
}

// ---------------- x fp32 [b][c][n] -> xT bf16 [b][n][PADC]  (transpose)
__global__ __launch_bounds__(256)
void x2t(const float* __restrict__ x, unsigned short* __restrict__ xT) {
  __shared__ unsigned short tile[64 * PADC];
  int t = threadIdx.x;
  int n0 = blockIdx.x * 64;
  int b = blockIdx.y;
  #pragma unroll
  for (int i = 0; i < 12; ++i) {
    int idx = t + i * 256;                 // 0..3071 float4 chunks
    int c = idx >> 4;                      // 0..191
    int nn4 = (idx & 15) << 2;             // 0..60
    float4 v = *(const float4*)(x + ((size_t)b * CDIM + c) * NPIX + n0 + nn4);
    tile[(nn4 + 0) * PADC + c] = f2b(v.x);
    tile[(nn4 + 1) * PADC + c] = f2b(v.y);
    tile[(nn4 + 2) * PADC + c] = f2b(v.z);
    tile[(nn4 + 3) * PADC + c] = f2b(v.w);
  }
  __syncthreads();
  #pragma unroll
  for (int i = 0; i < 6; ++i) {
    int idx = t + i * 256;                 // 0..1535 : 64 rows x 24 chunks
    int row = idx / 24;
    int c8 = (idx % 24) * 8;
    *(u16x8*)(xT + ((size_t)b * NPIX + n0 + row) * PADC + c8) =
        *(const u16x8*)(tile + row * PADC + c8);
  }
}

// ---------------- qkv GEMM, stationary-W-in-registers.
// Block = (n-group of GNT 64-pixel tiles, m-tile 0..5, batch). W m-tile
// fragments (24 bf16x8 = 96 VGPR) + biases loaded ONCE; loop GNT pixel
// tiles: stage b_lds -> barrier -> 6 ds_read + 24 MFMA -> stores -> barrier.
__global__ __launch_bounds__(256)
void gemm_t(const unsigned short* __restrict__ wq0,   // [192][PADC] bf16
            const unsigned short* __restrict__ wq1,   // [192][PADC] bf16
            const float* __restrict__ bias0,          // [192]
            const float* __restrict__ bias1,          // [192]
            const unsigned short* __restrict__ Bsrc,  // [2][NPIX][PADC] bf16
            unsigned short* __restrict__ outB)        // [4][192][N] bf16
{
  __shared__ unsigned short b_lds[64 * PADC];   // pixel tile (64 n x 192 c)
  int t = threadIdx.x;
  int mt = blockIdx.y;                // 0..5
  int half = mt / 3;                  // which quarter (0: wq0, 1: wq1)
  int mrow = (mt % 3) * 64;           // m-tile base within the 192-row quarter
  int b = blockIdx.z;
  int wid = t >> 6, lane = t & 63;
  int r = lane & 15, quad = lane >> 4;

  const unsigned short* wq = (half ? wq1 : wq0) + (size_t)mrow * PADC;
  bf16x8 wreg[4][6];                  // [nt][kk] W fragments, registers
  #pragma unroll
  for (int nt = 0; nt < 4; ++nt) {
    #pragma unroll
    for (int k6 = 0; k6 < 6; ++k6)
      wreg[nt][k6] = *(const bf16x8*)(wq + (size_t)(nt * 16 + r) * PADC + k6 * 32 + quad * 8);
  }
  const float* bp = half ? bias1 : bias0;
  float bb[4];
  #pragma unroll
  for (int nt = 0; nt < 4; ++nt) bb[nt] = bp[mrow + nt * 16 + r];

  unsigned short* op = outB + (size_t)(b * 2 + half) * CDIM * NPIX;

  for (int ni = 0; ni < GNT; ++ni) {
    int n0 = (blockIdx.x * GNT + ni) * 64;
    const unsigned short* Bs = Bsrc + ((size_t)b * NPIX + n0) * PADC;
    #pragma unroll
    for (int i = 0; i < 6; ++i) {
      int idx = t + i * 256;
      *(u16x8*)(b_lds + idx * 8) = *(const u16x8*)(Bs + (size_t)idx * 8);
    }
    if (t < 64) {
      int idx = 1536 + t;
      *(u16x8*)(b_lds + idx * 8) = *(const u16x8*)(Bs + (size_t)idx * 8);
    }
    __syncthreads();

    f32x4 acc[4];
    #pragma unroll
    for (int nt = 0; nt < 4; ++nt) acc[nt] = (f32x4){0.f, 0.f, 0.f, 0.f};

    #pragma unroll
    for (int k6 = 0; k6 < 6; ++k6) {
      bf16x8 xf = *(const bf16x8*)(b_lds + (wid * 16 + r) * PADC + k6 * 32 + quad * 8);
      #pragma unroll
      for (int nt = 0; nt < 4; ++nt)
        acc[nt] = __builtin_amdgcn_mfma_f32_16x16x32_bf16(xf, wreg[nt][k6], acc[nt], 0, 0, 0);
    }

    // D: row(M=n) = quad*4+i, col(N=m) = lane&15. Per lane: 4 consecutive n.
    size_t n = (size_t)n0 + wid * 16 + quad * 4;
    #pragma unroll
    for (int nt = 0; nt < 4; ++nt) {
      int m = mrow + nt * 16 + r;
      ushort4 uu;
      uu.x = f2b(acc[nt][0] + bb[nt]); uu.y = f2b(acc[nt][1] + bb[nt]);
      uu.z = f2b(acc[nt][2] + bb[nt]); uu.w = f2b(acc[nt][3] + bb[nt]);
      *(ushort4*)(op + (size_t)m * NPIX + n) = uu;
    }
    __syncthreads();                  // b_lds safe to overwrite next ni
  }
}

// ---------------- proj with fused PV+gate B-stage (round-11 form).
// Per block (64-pixel tile, batch b): for each head h, compute the att^T
// sub-tile D[c=32][n=64] = P[h] @ v[h] via MFMA (A=P bf16 from global,
// B=v via 8 u16 global reads per lane), multiply by sigmoid(gate), write
// b_lds[n][c]. Then 3 m-tiles: stage W into a_lds, MFMA, fp32 out c-major.
__global__ __launch_bounds__(256)
void proj_fused(const unsigned short* __restrict__ wproj,  // [192][PADC] bf16
                const float* __restrict__ bias,            // [192]
                const unsigned short* __restrict__ post2,  // [4][192][N]: b*2+{0:v,1:g}
                const unsigned short* __restrict__ Pbf,    // [2][HEADS][32][32] bf16 [c][d]
                float* __restrict__ out)                   // [2][192][N] fp32
{
  __shared__ unsigned short a_lds[64 * PADC];   // W tile
  __shared__ unsigned short b_lds[64 * PADC];   // att^T tile [n][c]
  int t = threadIdx.x;
  int n0 = blockIdx.x * 64;
  int b = blockIdx.y;
  int wid = t >> 6, lane = t & 63;
  int r = lane & 15, quad = lane >> 4;
  int nl = wid * 16 + r;                        // local n this lane owns
  size_t n = (size_t)n0 + nl;

  const unsigned short* vbase = post2 + (size_t)(b * 2 + 0) * CDIM * NPIX;
  const unsigned short* gbase = post2 + (size_t)(b * 2 + 1) * CDIM * NPIX;
  const unsigned short* Pb = Pbf + (size_t)b * HEADS * 1024;

  #pragma unroll
  for (int h = 0; h < HEADS; ++h) {
    // B-frag: v[k=quad*8+j][n], k within head h
    union { unsigned short u[8]; bf16x8 v; } vf;
    #pragma unroll
    for (int j = 0; j < 8; ++j)
      vf.u[j] = vbase[(size_t)(h * 32 + quad * 8 + j) * NPIX + n];
    #pragma unroll
    for (int c0 = 0; c0 < 32; c0 += 16) {
      // A-frag: P[c0+r][quad*8 .. +7] contiguous bf16x8 (L2-resident)
      bf16x8 pf = *(const bf16x8*)(Pb + h * 1024 + (c0 + r) * 32 + quad * 8);
      f32x4 d = (f32x4){0.f, 0.f, 0.f, 0.f};
      d = __builtin_amdgcn_mfma_f32_16x16x32_bf16(pf, vf.v, d, 0, 0, 0);
      // D: row c = c0 + quad*4 + i, col n = r (this lane's nl)
      #pragma unroll
      for (int i = 0; i < 4; ++i) {
        int c = c0 + quad * 4 + i;
        float gg = b2f(gbase[(size_t)(h * 32 + c) * NPIX + n]);
        float sg = 1.f / (1.f + __expf(-gg));
        b_lds[nl * PADC + h * 32 + c] = f2b(d[i] * sg);
      }
    }
  }

  #pragma unroll
  for (int mt = 0; mt < 3; ++mt) {
    int mrow = mt * 64;
    const unsigned short* wq = wproj + (size_t)mrow * PADC;

    __syncthreads();                    // b_lds ready (mt=0) / prev a reads done
    #pragma unroll
    for (int i = 0; i < 6; ++i) {
      int idx = t + i * 256;
      *(u16x8*)(a_lds + idx * 8) = *(const u16x8*)(wq + (size_t)idx * 8);
    }
    if (t < 64) {
      int idx = 1536 + t;
      *(u16x8*)(a_lds + idx * 8) = *(const u16x8*)(wq + (size_t)idx * 8);
    }
    __syncthreads();

    f32x4 acc[4];
    #pragma unroll
    for (int nt = 0; nt < 4; ++nt) acc[nt] = (f32x4){0.f, 0.f, 0.f, 0.f};

    #pragma unroll
    for (int kk = 0; kk < 192; kk += 32) {
      bf16x8 xf = *(const bf16x8*)(b_lds + (wid * 16 + r) * PADC + kk + quad * 8);
      #pragma unroll
      for (int nt = 0; nt < 4; ++nt) {
        bf16x8 wf = *(const bf16x8*)(a_lds + (nt * 16 + r) * PADC + kk + quad * 8);
        acc[nt] = __builtin_amdgcn_mfma_f32_16x16x32_bf16(xf, wf, acc[nt], 0, 0, 0);
      }
    }

    size_t nn = (size_t)n0 + wid * 16 + quad * 4;
    float* op = out + (size_t)b * CDIM * NPIX;
    #pragma unroll
    for (int nt = 0; nt < 4; ++nt) {
      int m = mrow + nt * 16 + r;
      float bbv = bias[m];
      float4 vv;
      vv.x = acc[nt][0] + bbv; vv.y = acc[nt][1] + bbv;
      vv.z = acc[nt][2] + bbv; vv.w = acc[nt][3] + bbv;
      *(float4*)(op + (size_t)m * NPIX + nn) = vv;
    }
  }
}

// ---------------- 3x3 depthwise conv + bias; optional fused per-channel ssq.
__global__ __launch_bounds__(256)
void dwconv_ssq(const unsigned short* __restrict__ in,   // [z][192][H][W] bf16
                const float* __restrict__ w9,            // [4][192][9] fp32
                const float* __restrict__ bias,          // [4][192] fp32
                unsigned short* __restrict__ outp,       // [z][192][H][W] bf16
                float* __restrict__ ssqBase,             // [2][2][192] or null
                int qs0, int qs1)
{
  __shared__ unsigned short lds[34][256];   // rows y0-1 .. y0+32
  __shared__ float red[4];
  int t = threadIdx.x;
  int z = blockIdx.z;
  int qsel = (z & 1) ? qs1 : qs0;
  int o  = blockIdx.x >> 3;                 // channel 0..191
  int ry = blockIdx.x & 7;                  // row group 0..7
  int y0 = ry << 5;                         // first output row

  const unsigned short* base = in + ((size_t)z * CDIM + o) * NPIX;
  #pragma unroll
  for (int i = 0; i < 9; ++i) {
    int idx = t + i * 256;
    if (idx < 2176) {
      int row = idx >> 6;
      int c4  = (idx & 63) << 2;
      int gy  = y0 - 1 + row;
      ushort4 vv = make_ushort4(0, 0, 0, 0);       // zero-pad y boundary
      if (gy >= 0 && gy < HH)
        vv = *(const ushort4*)(base + (size_t)gy * WW + c4);
      *(ushort4*)(&lds[row][c4]) = vv;
    }
  }

  float wv[9];
  #pragma unroll
  for (int i = 0; i < 9; ++i) wv[i] = w9[((size_t)qsel * CDIM + o) * 9 + i];
  float bo = bias[qsel * CDIM + o];
  __syncthreads();

  int w = t >> 6, lane = t & 63;
  int x0 = lane << 2;                       // 4 columns per lane
  float sumsq = 0.f;
  unsigned short* outbase = outp + ((size_t)z * CDIM + o) * NPIX;

  #pragma unroll
  for (int i = 0; i < 8; ++i) {
    int yo = w * 8 + i;                     // local output row (0..31)
    float a0 = bo, a1 = bo, a2 = bo, a3 = bo;
    #pragma unroll
    for (int dy = 0; dy < 3; ++dy) {
      ushort4 mv = *(const ushort4*)(&lds[yo + dy][x0]);   // ds_read_b64
      float v0 = b2f(mv.x), v1 = b2f(mv.y), v2 = b2f(mv.z), v3 = b2f(mv.w);
      float vl = __shfl_up(v3, 1, 64);   if (lane == 0)  vl = 0.f;  // x=-1
      float vr = __shfl_down(v0, 1, 64); if (lane == 63) vr = 0.f;  // x=256
      float w0 = wv[dy * 3 + 0], w1 = wv[dy * 3 + 1], w2 = wv[dy * 3 + 2];
      a0 += w0 * vl + w1 * v0 + w2 * v1;
      a1 += w0 * v0 + w1 * v1 + w2 * v2;
      a2 += w0 * v1 + w1 * v2 + w2 * v3;
      a3 += w0 * v2 + w1 * v3 + w2 * vr;
    }
    ushort4 ov;
    ov.x = f2b(a0); ov.y = f2b(a1); ov.z = f2b(a2); ov.w = f2b(a3);
    *(ushort4*)(outbase + (size_t)(y0 + yo) * WW + x0) = ov;    // 8B store
    if (ssqBase != nullptr) sumsq += a0 * a0 + a1 * a1 + a2 * a2 + a3 * a3;
  }

  if (ssqBase != nullptr) {                 // uniform per launch
    float* ssq = ssqBase + (size_t)(z >> 1) * 2 * CDIM + (z & 1) * CDIM;
    #pragma unroll
    for (int off = 32; off; off >>= 1) sumsq += __shfl_down(sumsq, off, 64);
    if (lane == 0) red[w] = sumsq;
    __syncthreads();
    if (t == 0) atomicAdd(&ssq[o], red[0] + red[1] + red[2] + red[3]);
  }
}

// ---------------- Gram: S[b][h][c][d] = sum_n q[...]*k[...]  (unchanged)
__global__ __launch_bounds__(256)
void gram(const unsigned short* __restrict__ post,   // [4][192][N] bf16
          float* __restrict__ S)                     // [2][HEADS][32][32]
{
  int h = blockIdx.y, b = blockIdx.z;
  int t = threadIdx.x, wid = t >> 6, lane = t & 63;
  int r = lane & 15, quad = lane >> 4;
  int c0 = (wid >> 1) * 16, d0 = (wid & 1) * 16;
  size_t nb = (size_t)blockIdx.x * 512 + quad * 8;
  const unsigned short* qrow =
      post + ((size_t)(b * 2 + 0) * CDIM + h * 32 + c0 + r) * NPIX + nb;
  const unsigned short* krow =
      post + ((size_t)(b * 2 + 1) * CDIM + h * 32 + d0 + r) * NPIX + nb;
  f32x4 acc = (f32x4){0.f, 0.f, 0.f, 0.f};
  #pragma unroll
  for (int kk = 0; kk < 512; kk += 32) {
    bf16x8 af  = *(const bf16x8*)(qrow + kk);
    bf16x8 bfr = *(const bf16x8*)(krow + kk);
    acc = __builtin_amdgcn_mfma_f32_16x16x32_bf16(af, bfr, acc, 0, 0, 0);
  }
  float* Sp = S + ((size_t)b * HEADS + h) * 1024;
  #pragma unroll
  for (int i = 0; i < 4; ++i)
    atomicAdd(&Sp[(c0 + quad * 4 + i) * 32 + (d0 + r)], acc[i]);
}

// ---------------- scale + softmax; writes P as bf16 [b][h][c][d]
__global__ void softmax_scale(const float* __restrict__ S,    // [2][HEADS][1024]
                              const float* __restrict__ ssq,  // [2][2][192]
                              const float* __restrict__ temp, // [HEADS]
                              unsigned short* __restrict__ Pbf) // [2][HEADS][32][32] bf16
{
  int h = blockIdx.x, b = blockIdx.y;
  int t = threadIdx.x;
  int c = t >> 5, d = t & 31;
  float nq = fmaxf(sqrtf(ssq[(size_t)b * 2 * CDIM + h * 32 + c]), 1e-12f);
  float nk = fmaxf(sqrtf(ssq[(size_t)b * 2 * CDIM + CDIM + h * 32 + d]), 1e-12f);
  float v = S[((size_t)b * HEADS + h) * 1024 + t] / (nq * nk) * temp[h];
  float m = v;
  for (int off = 16; off; off >>= 1) m = fmaxf(m, __shfl_xor(m, off, 32));
  float e = expf(v - m);
  float s = e;
  for (int off = 16; off; off >>= 1) s += __shfl_xor(s, off, 32);
  Pbf[((size_t)b * HEADS + h) * 1024 + c * 32 + d] = f2b(e / s);
}

extern "C" void kernel_launch(void* const* d_in, const int* in_sizes, int n_in,
                              void* d_out, int out_size, void* d_ws, size_t ws_size,
                              hipStream_t stream)
{
  const float* x      = (const float*)d_in[0];
  const float* qkv_w  = (const float*)d_in[1];
  const float* qkv_b  = (const float*)d_in[2];
  const float* dw_w   = (const float*)d_in[3];
  const float* dw_b   = (const float*)d_in[4];
  const float* temp   = (const float*)d_in[5];
  const float* proj_w = (const float*)d_in[6];
  const float* proj_b = (const float*)d_in[7];
  float* out = (float*)d_out;

  char* ws = (char*)d_ws;
  const size_t qbytes  = (size_t)CDIM * NPIX * 2;            // 25,165,824
  const size_t xTbytes = (size_t)2 * NPIX * PADC * 2;        // 52,428,800
  const size_t wbytes  = (size_t)5 * 192 * PADC * 2;         // 384,000
  unsigned short* xT    = (unsigned short*)ws;
  unsigned short* wbf   = (unsigned short*)(ws + xTbytes);
  unsigned short* pre   = (unsigned short*)(ws + xTbytes + wbytes);          // 4 slots
  unsigned short* post  = (unsigned short*)(ws + xTbytes + wbytes + 4 * qbytes);
  unsigned short* post2 = (unsigned short*)(ws + xTbytes + wbytes + 8 * qbytes);
  float* S   = (float*)(ws + xTbytes + wbytes + 12 * qbytes);
  float* ssq = S + 2 * HEADS * 1024;
  unsigned short* Pbf = (unsigned short*)(ssq + 2 * 2 * CDIM);  // [2][6][32][32] bf16
  const int nz = 2 * HEADS * 1024 + 2 * 2 * CDIM;

  zero_init<<<(nz + 255) / 256, 256, 0, stream>>>(S, nz);
  w2bf<<<(5 * 192 * 192 + 255) / 256, 256, 0, stream>>>(qkv_w, proj_w, wbf);
  x2t<<<dim3(NPIX / 64, 2), 256, 0, stream>>>(x, xT);

  const unsigned short* wq = wbf;                      // quarter stride 192*PADC
  const size_t wqs = (size_t)192 * PADC;

  // phase 1: q (quarter 0) + k (quarter 2), both batches -> pre slots b*2+{0,1}
  gemm_t<<<dim3(NPIX / (64 * GNT), 6, 2), 256, 0, stream>>>(
      wq + 0 * wqs, wq + 2 * wqs, qkv_b + 0 * CDIM, qkv_b + 2 * CDIM, xT, pre);
  dwconv_ssq<<<dim3(CDIM * 8, 1, 4), 256, 0, stream>>>(pre, dw_w, dw_b, post, ssq, 0, 2);

  // phase 2: v (quarter 3) + gate (quarter 1) -> pre slots b*2+{0,1}
  gemm_t<<<dim3(NPIX / (64 * GNT), 6, 2), 256, 0, stream>>>(
      wq + 3 * wqs, wq + 1 * wqs, qkv_b + 3 * CDIM, qkv_b + 1 * CDIM, xT, pre);
  dwconv_ssq<<<dim3(CDIM * 8, 1, 4), 256, 0, stream>>>(pre, dw_w, dw_b, post2, nullptr, 3, 1);

  gram<<<dim3(128, HEADS, 2), 256, 0, stream>>>(post, S);
  softmax_scale<<<dim3(HEADS, 2), 1024, 0, stream>>>(S, ssq, temp, Pbf);

  // proj with fused PV+gate B-stage, fp32 out c-major
  proj_fused<<<dim3(NPIX / 64, 2), 256, 0, stream>>>(
      wq + 4 * wqs, proj_b, post2, Pbf, out);
}

// Round 9
// 484.192 us; speedup vs baseline: 1.3743x; 1.0584x over previous
//
#include <hip/hip_runtime.h>
#include <math.h>

// GatedMDTA: B=2, C=192, H=W=256, HEADS=6, hd=32, QC=768.
// Round 14: two latency fixes on the round-13 (512us) structure.
// 1) gemm_t: register-prefetch double-buffer (T14 issue-early/write-late).
//    GNT 4->8; per tile: {ds_write staged regs -> barrier -> issue next
//    tile's 7 global loads -> ds_read + 24 MFMA + stores -> barrier}.
//    Round-13 counters (MfmaUtil 10%, VALU 12%, HBM 28%, occ 27%) showed the
//    single-buffered loop pays full staging latency serially per tile.
// 2) proj_fused: PV phase's 96 scattered 2B global loads/lane (v+gate at
//    128KB stride) replaced by coalesced 16B/lane staging of v/g tiles into
//    LDS ([192][68] u16, 8B-aligned rows, <=4-way banks), PV reads via
//    ds_read_u16; gated att held in 48 regs; LDS union-reused for the
//    unchanged b_lds/a_lds m-tile loop.
// Everything else identical to round 13.
//
// ws layout: xT 52.43MB | wbf 0.38MB | pre 4q | post 4q | post2 4q |
//            S/ssq floats | Pbf bf16.  Total ~330MB < 402MB ws.

#define HEADS 6
#define CDIM 192
#define QCH 768
#define HH 256
#define WW 256
#define NPIX 65536
#define PADC 200   // padded channel row stride (ushorts)
#define GNT 8      // n-tiles per gemm_t block

typedef __bf16 bf16x8 __attribute__((ext_vector_type(8)));
typedef float f32x4 __attribute__((ext_vector_type(4)));
typedef unsigned short u16x8 __attribute__((ext_vector_type(8)));
typedef unsigned short u16x4 __attribute__((ext_vector_type(4)));

__device__ __forceinline__ float b2f(unsigned short u) {
  union { unsigned int i; float f; } x; x.i = ((unsigned int)u) << 16; return x.f;
}
__device__ __forceinline__ unsigned short f2b(float f) {
  union { float f; unsigned int i; } x; x.f = f;
  unsigned int lsb = (x.i >> 16) & 1u;
  x.i += 0x7fffu + lsb;           // round-to-nearest-even
  return (unsigned short)(x.i >> 16);
}

// ---------------- zero-init small fp32 scratch
__global__ void zero_init(float* __restrict__ p, int n) {
  int i = blockIdx.x * 256 + threadIdx.x;
  if (i < n) p[i] = 0.f;
}

// ---------------- weights fp32 -> bf16, padded rows [5][192][200]
// q 0..3 = qkv quarters, q 4 = proj.
__global__ __launch_bounds__(256)
void w2bf(const float* __restrict__ qkv_w, const float* __restrict__ proj_w,
          unsigned short* __restrict__ wbf) {
  int id = blockIdx.x * 256 + threadIdx.x;      // < 5*192*192 = 184320
  if (id >= 5 * 192 * 192) return;
  int k = id % 192;
  int m = (id / 192) % 192;
  int q = id / (192 * 192);
  float v = (q < 4) ? qkv_w[(size_t)(q * 192 + m) * 192 + k]
                    : proj_w[(size_t)m * 192 + k];
  wbf[((size_t)q * 192 + m) * PADC + k] = f2b(v);
}

// ---------------- x fp32 [b][c][n] -> xT bf16 [b][n][PADC]  (transpose)
__global__ __launch_bounds__(256)
void x2t(const float* __restrict__ x, unsigned short* __restrict__ xT) {
  __shared__ unsigned short tile[64 * PADC];
  int t = threadIdx.x;
  int n0 = blockIdx.x * 64;
  int b = blockIdx.y;
  #pragma unroll
  for (int i = 0; i < 12; ++i) {
    int idx = t + i * 256;                 // 0..3071 float4 chunks
    int c = idx >> 4;                      // 0..191
    int nn4 = (idx & 15) << 2;             // 0..60
    float4 v = *(const float4*)(x + ((size_t)b * CDIM + c) * NPIX + n0 + nn4);
    tile[(nn4 + 0) * PADC + c] = f2b(v.x);
    tile[(nn4 + 1) * PADC + c] = f2b(v.y);
    tile[(nn4 + 2) * PADC + c] = f2b(v.z);
    tile[(nn4 + 3) * PADC + c] = f2b(v.w);
  }
  __syncthreads();
  #pragma unroll
  for (int i = 0; i < 6; ++i) {
    int idx = t + i * 256;                 // 0..1535 : 64 rows x 24 chunks
    int row = idx / 24;
    int c8 = (idx % 24) * 8;
    *(u16x8*)(xT + ((size_t)b * NPIX + n0 + row) * PADC + c8) =
        *(const u16x8*)(tile + row * PADC + c8);
  }
}

// ---------------- qkv GEMM, stationary-W-in-registers + prefetch dbuf.
// Block = (n-group of GNT 64-pixel tiles, m-tile 0..5, batch). W m-tile
// fragments (24 bf16x8 = 96 VGPR) + biases loaded ONCE. Per tile:
// {ds_write staged regs -> barrier -> issue next tile's global loads ->
//  6 ds_read + 24 MFMA -> stores -> barrier} — load latency hides under
// compute/stores of the current tile.
__global__ __launch_bounds__(256)
void gemm_t(const unsigned short* __restrict__ wq0,   // [192][PADC] bf16
            const unsigned short* __restrict__ wq1,   // [192][PADC] bf16
            const float* __restrict__ bias0,          // [192]
            const float* __restrict__ bias1,          // [192]
            const unsigned short* __restrict__ Bsrc,  // [2][NPIX][PADC] bf16
            unsigned short* __restrict__ outB)        // [4][192][N] bf16
{
  __shared__ unsigned short b_lds[64 * PADC];   // pixel tile (64 n x 192 c)
  int t = threadIdx.x;
  int mt = blockIdx.y;                // 0..5
  int half = mt / 3;                  // which quarter (0: wq0, 1: wq1)
  int mrow = (mt % 3) * 64;           // m-tile base within the 192-row quarter
  int b = blockIdx.z;
  int wid = t >> 6, lane = t & 63;
  int r = lane & 15, quad = lane >> 4;

  const unsigned short* wq = (half ? wq1 : wq0) + (size_t)mrow * PADC;
  bf16x8 wreg[4][6];                  // [nt][kk] W fragments, registers
  #pragma unroll
  for (int nt = 0; nt < 4; ++nt) {
    #pragma unroll
    for (int k6 = 0; k6 < 6; ++k6)
      wreg[nt][k6] = *(const bf16x8*)(wq + (size_t)(nt * 16 + r) * PADC + k6 * 32 + quad * 8);
  }
  const float* bp = half ? bias1 : bias0;
  float bb[4];
  #pragma unroll
  for (int nt = 0; nt < 4; ++nt) bb[nt] = bp[mrow + nt * 16 + r];

  unsigned short* op = outB + (size_t)(b * 2 + half) * CDIM * NPIX;

  // prefetch tile 0 into registers
  u16x8 st[6]; u16x8 st7;
  {
    const unsigned short* Bs = Bsrc + ((size_t)b * NPIX + (size_t)blockIdx.x * GNT * 64) * PADC;
    #pragma unroll
    for (int i = 0; i < 6; ++i)
      st[i] = *(const u16x8*)(Bs + (size_t)(t + i * 256) * 8);
    if (t < 64) st7 = *(const u16x8*)(Bs + (size_t)(1536 + t) * 8);
  }

  for (int ni = 0; ni < GNT; ++ni) {
    // write staged tile to LDS
    #pragma unroll
    for (int i = 0; i < 6; ++i)
      *(u16x8*)(b_lds + (t + i * 256) * 8) = st[i];
    if (t < 64) *(u16x8*)(b_lds + (1536 + t) * 8) = st7;
    __syncthreads();

    // issue next tile's loads (latency hidden under MFMA+stores below)
    if (ni + 1 < GNT) {
      const unsigned short* Bs =
          Bsrc + ((size_t)b * NPIX + ((size_t)blockIdx.x * GNT + ni + 1) * 64) * PADC;
      #pragma unroll
      for (int i = 0; i < 6; ++i)
        st[i] = *(const u16x8*)(Bs + (size_t)(t + i * 256) * 8);
      if (t < 64) st7 = *(const u16x8*)(Bs + (size_t)(1536 + t) * 8);
    }

    f32x4 acc[4];
    #pragma unroll
    for (int nt = 0; nt < 4; ++nt) acc[nt] = (f32x4){0.f, 0.f, 0.f, 0.f};

    #pragma unroll
    for (int k6 = 0; k6 < 6; ++k6) {
      bf16x8 xf = *(const bf16x8*)(b_lds + (wid * 16 + r) * PADC + k6 * 32 + quad * 8);
      #pragma unroll
      for (int nt = 0; nt < 4; ++nt)
        acc[nt] = __builtin_amdgcn_mfma_f32_16x16x32_bf16(xf, wreg[nt][k6], acc[nt], 0, 0, 0);
    }

    // D: row(M=n) = quad*4+i, col(N=m) = lane&15. Per lane: 4 consecutive n.
    int n0 = ((int)blockIdx.x * GNT + ni) * 64;
    size_t n = (size_t)n0 + wid * 16 + quad * 4;
    #pragma unroll
    for (int nt = 0; nt < 4; ++nt) {
      int m = mrow + nt * 16 + r;
      ushort4 uu;
      uu.x = f2b(acc[nt][0] + bb[nt]); uu.y = f2b(acc[nt][1] + bb[nt]);
      uu.z = f2b(acc[nt][2] + bb[nt]); uu.w = f2b(acc[nt][3] + bb[nt]);
      *(ushort4*)(op + (size_t)m * NPIX + n) = uu;
    }
    __syncthreads();                  // b_lds safe to overwrite next ni
  }
}

// ---------------- proj with fused PV+gate; v/g staged in LDS (coalesced).
// Phase A: stage v,g tiles ([192][68] u16 each, 8B-aligned rows) with 16B/lane
// global loads; PV per head: 8 ds_read_u16 (v) + MFMA(A=P from global) +
// 8 ds_read_u16 (g) + sigmoid; gated att kept in 48 regs.
// Phase B (LDS union-reused): write b_lds[n][c], then 3 m-tiles of
// {stage W into a_lds, MFMA}, fp32 out c-major. (round-11 compute tail)
__global__ __launch_bounds__(256)
void proj_fused(const unsigned short* __restrict__ wproj,  // [192][PADC] bf16
                const float* __restrict__ bias,            // [192]
                const unsigned short* __restrict__ post2,  // [4][192][N]: b*2+{0:v,1:g}
                const unsigned short* __restrict__ Pbf,    // [2][HEADS][32][32] bf16 [c][d]
                float* __restrict__ out)                   // [2][192][N] fp32
{
  __shared__ unsigned char smem[52224];
  unsigned short* v_lds = (unsigned short*)smem;            // [192][68] phase A
  unsigned short* g_lds = (unsigned short*)(smem + 26112);  // [192][68] phase A
  unsigned short* b_l   = (unsigned short*)smem;            // [64][PADC] phase B
  unsigned short* a_l   = (unsigned short*)(smem + 25600);  // [64][PADC] phase B

  int t = threadIdx.x;
  int n0 = blockIdx.x * 64;
  int b = blockIdx.y;
  int wid = t >> 6, lane = t & 63;
  int r = lane & 15, quad = lane >> 4;
  int nl = wid * 16 + r;                        // local n this lane owns

  const unsigned short* vbase = post2 + (size_t)(b * 2 + 0) * CDIM * NPIX;
  const unsigned short* gbase = post2 + (size_t)(b * 2 + 1) * CDIM * NPIX;
  const unsigned short* Pb = Pbf + (size_t)b * HEADS * 1024;

  // ---- phase A: stage v,g (192 rows x 64 cols each; 1536 16B chunks each)
  #pragma unroll
  for (int i = 0; i < 6; ++i) {
    int idx = t + i * 256;                 // 0..1535
    int row = idx >> 3, sub = idx & 7;
    u16x8 vv = *(const u16x8*)(vbase + (size_t)row * NPIX + n0 + sub * 8);
    u16x8 gg = *(const u16x8*)(gbase + (size_t)row * NPIX + n0 + sub * 8);
    unsigned short* vd = v_lds + row * 68 + sub * 8;   // 136B row stride: 8B-aligned
    unsigned short* gd = g_lds + row * 68 + sub * 8;
    *(u16x4*)(vd)     = (u16x4){vv[0], vv[1], vv[2], vv[3]};
    *(u16x4*)(vd + 4) = (u16x4){vv[4], vv[5], vv[6], vv[7]};
    *(u16x4*)(gd)     = (u16x4){gg[0], gg[1], gg[2], gg[3]};
    *(u16x4*)(gd + 4) = (u16x4){gg[4], gg[5], gg[6], gg[7]};
  }
  __syncthreads();

  float attr[HEADS][8];
  #pragma unroll
  for (int h = 0; h < HEADS; ++h) {
    union { unsigned short u[8]; bf16x8 v; } vf;
    #pragma unroll
    for (int j = 0; j < 8; ++j)
      vf.u[j] = v_lds[(h * 32 + quad * 8 + j) * 68 + nl];
    #pragma unroll
    for (int c8 = 0; c8 < 2; ++c8) {
      int c0 = c8 * 16;
      bf16x8 pf = *(const bf16x8*)(Pb + h * 1024 + (c0 + r) * 32 + quad * 8);
      f32x4 d = (f32x4){0.f, 0.f, 0.f, 0.f};
      d = __builtin_amdgcn_mfma_f32_16x16x32_bf16(pf, vf.v, d, 0, 0, 0);
      #pragma unroll
      for (int i = 0; i < 4; ++i) {
        int c = c0 + quad * 4 + i;
        float gg = b2f(g_lds[(h * 32 + c) * 68 + nl]);
        attr[h][c8 * 4 + i] = d[i] / (1.f + __expf(-gg));
      }
    }
  }
  __syncthreads();   // all v/g LDS reads done; smem reused as b_l/a_l

  // ---- phase B: write att^T tile, then proj m-tile loop
  #pragma unroll
  for (int h = 0; h < HEADS; ++h) {
    #pragma unroll
    for (int c8 = 0; c8 < 2; ++c8) {
      #pragma unroll
      for (int i = 0; i < 4; ++i)
        b_l[nl * PADC + h * 32 + c8 * 16 + quad * 4 + i] = f2b(attr[h][c8 * 4 + i]);
    }
  }

  #pragma unroll
  for (int mt = 0; mt < 3; ++mt) {
    int mrow = mt * 64;
    const unsigned short* wq = wproj + (size_t)mrow * PADC;

    __syncthreads();                    // b_l writes visible / prev a reads done
    #pragma unroll
    for (int i = 0; i < 6; ++i) {
      int idx = t + i * 256;
      *(u16x8*)(a_l + idx * 8) = *(const u16x8*)(wq + (size_t)idx * 8);
    }
    if (t < 64) {
      int idx = 1536 + t;
      *(u16x8*)(a_l + idx * 8) = *(const u16x8*)(wq + (size_t)idx * 8);
    }
    __syncthreads();

    f32x4 acc[4];
    #pragma unroll
    for (int nt = 0; nt < 4; ++nt) acc[nt] = (f32x4){0.f, 0.f, 0.f, 0.f};

    #pragma unroll
    for (int kk = 0; kk < 192; kk += 32) {
      bf16x8 xf = *(const bf16x8*)(b_l + (wid * 16 + r) * PADC + kk + quad * 8);
      #pragma unroll
      for (int nt = 0; nt < 4; ++nt) {
        bf16x8 wf = *(const bf16x8*)(a_l + (nt * 16 + r) * PADC + kk + quad * 8);
        acc[nt] = __builtin_amdgcn_mfma_f32_16x16x32_bf16(xf, wf, acc[nt], 0, 0, 0);
      }
    }

    size_t nn = (size_t)n0 + wid * 16 + quad * 4;
    float* op = out + (size_t)b * CDIM * NPIX;
    #pragma unroll
    for (int nt = 0; nt < 4; ++nt) {
      int m = mrow + nt * 16 + r;
      float bbv = bias[m];
      float4 vv;
      vv.x = acc[nt][0] + bbv; vv.y = acc[nt][1] + bbv;
      vv.z = acc[nt][2] + bbv; vv.w = acc[nt][3] + bbv;
      *(float4*)(op + (size_t)m * NPIX + nn) = vv;
    }
  }
}

// ---------------- 3x3 depthwise conv + bias; optional fused per-channel ssq.
__global__ __launch_bounds__(256)
void dwconv_ssq(const unsigned short* __restrict__ in,   // [z][192][H][W] bf16
                const float* __restrict__ w9,            // [4][192][9] fp32
                const float* __restrict__ bias,          // [4][192] fp32
                unsigned short* __restrict__ outp,       // [z][192][H][W] bf16
                float* __restrict__ ssqBase,             // [2][2][192] or null
                int qs0, int qs1)
{
  __shared__ unsigned short lds[34][256];   // rows y0-1 .. y0+32
  __shared__ float red[4];
  int t = threadIdx.x;
  int z = blockIdx.z;
  int qsel = (z & 1) ? qs1 : qs0;
  int o  = blockIdx.x >> 3;                 // channel 0..191
  int ry = blockIdx.x & 7;                  // row group 0..7
  int y0 = ry << 5;                         // first output row

  const unsigned short* base = in + ((size_t)z * CDIM + o) * NPIX;
  #pragma unroll
  for (int i = 0; i < 9; ++i) {
    int idx = t + i * 256;
    if (idx < 2176) {
      int row = idx >> 6;
      int c4  = (idx & 63) << 2;
      int gy  = y0 - 1 + row;
      ushort4 vv = make_ushort4(0, 0, 0, 0);       // zero-pad y boundary
      if (gy >= 0 && gy < HH)
        vv = *(const ushort4*)(base + (size_t)gy * WW + c4);
      *(ushort4*)(&lds[row][c4]) = vv;
    }
  }

  float wv[9];
  #pragma unroll
  for (int i = 0; i < 9; ++i) wv[i] = w9[((size_t)qsel * CDIM + o) * 9 + i];
  float bo = bias[qsel * CDIM + o];
  __syncthreads();

  int w = t >> 6, lane = t & 63;
  int x0 = lane << 2;                       // 4 columns per lane
  float sumsq = 0.f;
  unsigned short* outbase = outp + ((size_t)z * CDIM + o) * NPIX;

  #pragma unroll
  for (int i = 0; i < 8; ++i) {
    int yo = w * 8 + i;                     // local output row (0..31)
    float a0 = bo, a1 = bo, a2 = bo, a3 = bo;
    #pragma unroll
    for (int dy = 0; dy < 3; ++dy) {
      ushort4 mv = *(const ushort4*)(&lds[yo + dy][x0]);   // ds_read_b64
      float v0 = b2f(mv.x), v1 = b2f(mv.y), v2 = b2f(mv.z), v3 = b2f(mv.w);
      float vl = __shfl_up(v3, 1, 64);   if (lane == 0)  vl = 0.f;  // x=-1
      float vr = __shfl_down(v0, 1, 64); if (lane == 63) vr = 0.f;  // x=256
      float w0 = wv[dy * 3 + 0], w1 = wv[dy * 3 + 1], w2 = wv[dy * 3 + 2];
      a0 += w0 * vl + w1 * v0 + w2 * v1;
      a1 += w0 * v0 + w1 * v1 + w2 * v2;
      a2 += w0 * v1 + w1 * v2 + w2 * v3;
      a3 += w0 * v2 + w1 * v3 + w2 * vr;
    }
    ushort4 ov;
    ov.x = f2b(a0); ov.y = f2b(a1); ov.z = f2b(a2); ov.w = f2b(a3);
    *(ushort4*)(outbase + (size_t)(y0 + yo) * WW + x0) = ov;    // 8B store
    if (ssqBase != nullptr) sumsq += a0 * a0 + a1 * a1 + a2 * a2 + a3 * a3;
  }

  if (ssqBase != nullptr) {                 // uniform per launch
    float* ssq = ssqBase + (size_t)(z >> 1) * 2 * CDIM + (z & 1) * CDIM;
    #pragma unroll
    for (int off = 32; off; off >>= 1) sumsq += __shfl_down(sumsq, off, 64);
    if (lane == 0) red[w] = sumsq;
    __syncthreads();
    if (t == 0) atomicAdd(&ssq[o], red[0] + red[1] + red[2] + red[3]);
  }
}

// ---------------- Gram: S[b][h][c][d] = sum_n q[...]*k[...]  (unchanged)
__global__ __launch_bounds__(256)
void gram(const unsigned short* __restrict__ post,   // [4][192][N] bf16
          float* __restrict__ S)                     // [2][HEADS][32][32]
{
  int h = blockIdx.y, b = blockIdx.z;
  int t = threadIdx.x, wid = t >> 6, lane = t & 63;
  int r = lane & 15, quad = lane >> 4;
  int c0 = (wid >> 1) * 16, d0 = (wid & 1) * 16;
  size_t nb = (size_t)blockIdx.x * 512 + quad * 8;
  const unsigned short* qrow =
      post + ((size_t)(b * 2 + 0) * CDIM + h * 32 + c0 + r) * NPIX + nb;
  const unsigned short* krow =
      post + ((size_t)(b * 2 + 1) * CDIM + h * 32 + d0 + r) * NPIX + nb;
  f32x4 acc = (f32x4){0.f, 0.f, 0.f, 0.f};
  #pragma unroll
  for (int kk = 0; kk < 512; kk += 32) {
    bf16x8 af  = *(const bf16x8*)(qrow + kk);
    bf16x8 bfr = *(const bf16x8*)(krow + kk);
    acc = __builtin_amdgcn_mfma_f32_16x16x32_bf16(af, bfr, acc, 0, 0, 0);
  }
  float* Sp = S + ((size_t)b * HEADS + h) * 1024;
  #pragma unroll
  for (int i = 0; i < 4; ++i)
    atomicAdd(&Sp[(c0 + quad * 4 + i) * 32 + (d0 + r)], acc[i]);
}

// ---------------- scale + softmax; writes P as bf16 [b][h][c][d]
__global__ void softmax_scale(const float* __restrict__ S,    // [2][HEADS][1024]
                              const float* __restrict__ ssq,  // [2][2][192]
                              const float* __restrict__ temp, // [HEADS]
                              unsigned short* __restrict__ Pbf) // [2][HEADS][32][32] bf16
{
  int h = blockIdx.x, b = blockIdx.y;
  int t = threadIdx.x;
  int c = t >> 5, d = t & 31;
  float nq = fmaxf(sqrtf(ssq[(size_t)b * 2 * CDIM + h * 32 + c]), 1e-12f);
  float nk = fmaxf(sqrtf(ssq[(size_t)b * 2 * CDIM + CDIM + h * 32 + d]), 1e-12f);
  float v = S[((size_t)b * HEADS + h) * 1024 + t] / (nq * nk) * temp[h];
  float m = v;
  for (int off = 16; off; off >>= 1) m = fmaxf(m, __shfl_xor(m, off, 32));
  float e = expf(v - m);
  float s = e;
  for (int off = 16; off; off >>= 1) s += __shfl_xor(s, off, 32);
  Pbf[((size_t)b * HEADS + h) * 1024 + c * 32 + d] = f2b(e / s);
}

extern "C" void kernel_launch(void* const* d_in, const int* in_sizes, int n_in,
                              void* d_out, int out_size, void* d_ws, size_t ws_size,
                              hipStream_t stream)
{
  const float* x      = (const float*)d_in[0];
  const float* qkv_w  = (const float*)d_in[1];
  const float* qkv_b  = (const float*)d_in[2];
  const float* dw_w   = (const float*)d_in[3];
  const float* dw_b   = (const float*)d_in[4];
  const float* temp   = (const float*)d_in[5];
  const float* proj_w = (const float*)d_in[6];
  const float* proj_b = (const float*)d_in[7];
  float* out = (float*)d_out;

  char* ws = (char*)d_ws;
  const size_t qbytes  = (size_t)CDIM * NPIX * 2;            // 25,165,824
  const size_t xTbytes = (size_t)2 * NPIX * PADC * 2;        // 52,428,800
  const size_t wbytes  = (size_t)5 * 192 * PADC * 2;         // 384,000
  unsigned short* xT    = (unsigned short*)ws;
  unsigned short* wbf   = (unsigned short*)(ws + xTbytes);
  unsigned short* pre   = (unsigned short*)(ws + xTbytes + wbytes);          // 4 slots
  unsigned short* post  = (unsigned short*)(ws + xTbytes + wbytes + 4 * qbytes);
  unsigned short* post2 = (unsigned short*)(ws + xTbytes + wbytes + 8 * qbytes);
  float* S   = (float*)(ws + xTbytes + wbytes + 12 * qbytes);
  float* ssq = S + 2 * HEADS * 1024;
  unsigned short* Pbf = (unsigned short*)(ssq + 2 * 2 * CDIM);  // [2][6][32][32] bf16
  const int nz = 2 * HEADS * 1024 + 2 * 2 * CDIM;

  zero_init<<<(nz + 255) / 256, 256, 0, stream>>>(S, nz);
  w2bf<<<(5 * 192 * 192 + 255) / 256, 256, 0, stream>>>(qkv_w, proj_w, wbf);
  x2t<<<dim3(NPIX / 64, 2), 256, 0, stream>>>(x, xT);

  const unsigned short* wq = wbf;                      // quarter stride 192*PADC
  const size_t wqs = (size_t)192 * PADC;

  // phase 1: q (quarter 0) + k (quarter 2), both batches -> pre slots b*2+{0,1}
  gemm_t<<<dim3(NPIX / (64 * GNT), 6, 2), 256, 0, stream>>>(
      wq + 0 * wqs, wq + 2 * wqs, qkv_b + 0 * CDIM, qkv_b + 2 * CDIM, xT, pre);
  dwconv_ssq<<<dim3(CDIM * 8, 1, 4), 256, 0, stream>>>(pre, dw_w, dw_b, post, ssq, 0, 2);

  // phase 2: v (quarter 3) + gate (quarter 1) -> pre slots b*2+{0,1}
  gemm_t<<<dim3(NPIX / (64 * GNT), 6, 2), 256, 0, stream>>>(
      wq + 3 * wqs, wq + 1 * wqs, qkv_b + 3 * CDIM, qkv_b + 1 * CDIM, xT, pre);
  dwconv_ssq<<<dim3(CDIM * 8, 1, 4), 256, 0, stream>>>(pre, dw_w, dw_b, post2, nullptr, 3, 1);

  gram<<<dim3(128, HEADS, 2), 256, 0, stream>>>(post, S);
  softmax_scale<<<dim3(HEADS, 2), 1024, 0, stream>>>(S, ssq, temp, Pbf);

  // proj with fused PV+gate (LDS-staged v/g), fp32 out c-major
  proj_fused<<<dim3(NPIX / 64, 2), 256, 0, stream>>>(
      wq + 4 * wqs, proj_b, post2, Pbf, out);
}